// Round 4
// baseline (270.203 us; speedup 1.0000x reference)
//
#include <hip/hip_runtime.h>

__device__ __forceinline__ float4 exp4(float4 v) {
    float4 r;
    r.x = __expf(v.x); r.y = __expf(v.y); r.z = __expf(v.z); r.w = __expf(v.w);
    return r;
}

__device__ __forceinline__ void acc4(float4& a, float4 e) {
    a.x += e.x; a.y += e.y; a.z += e.z; a.w += e.w;
}

__device__ __forceinline__ float wave_reduce(float v) {
    #pragma unroll
    for (int off = 32; off > 0; off >>= 1) v += __shfl_down(v, off, 64);
    return v;
}

// ================= MEGA: blocks 0..127 theta1 path; blocks 128..4223 theta0 segment sums =====
// block = 256
__global__ __launch_bounds__(256) void MEGA(const float4* __restrict__ theta0,
                                            const float4* __restrict__ obs0,
                                            const int* __restrict__ idx,
                                            const float4* __restrict__ theta1,
                                            const float4* __restrict__ mapping1,
                                            float4* __restrict__ s0,   // nullptr => p2-atomics
                                            float* __restrict__ p2,
                                            float* __restrict__ lossA,
                                            float* __restrict__ m1) {
    const int t = threadIdx.x, lane = t & 63, wave = t >> 6;

    if (blockIdx.x < 128) {
        // ---- theta1 row sums of exp, then mapping1 slice -> m1 atomics ----
        const int b2 = blockIdx.x;               // col-slice of 32 p1-entries
        __shared__ float p1s[32];
        #pragma unroll
        for (int rr = 0; rr < 8; ++rr) {
            const int lr = wave * 8 + rr;        // 0..31
            const float4* rp = theta1 + (size_t)(b2 * 32 + lr) * 512;
            float a = 0.f;
            #pragma unroll
            for (int i = 0; i < 8; ++i) {
                const float4 x = rp[lane + i * 64];
                a += __expf(x.x) + __expf(x.y) + __expf(x.z) + __expf(x.w);
            }
            a = wave_reduce(a);
            if (lane == 0) p1s[lr] = a;
        }
        __syncthreads();
        #pragma unroll
        for (int rr = 0; rr < 2; ++rr) {
            const int r = t * 2 + rr;            // 0..511
            const float4* mp = mapping1 + (size_t)r * 1024 + b2 * 8;
            float s = 0.f;
            #pragma unroll
            for (int j = 0; j < 8; ++j) {
                const float4 m = mp[j];
                s += m.x * p1s[j*4+0] + m.y * p1s[j*4+1]
                   + m.z * p1s[j*4+2] + m.w * p1s[j*4+3];
            }
            atomicAdd(&m1[r], s);
        }
        return;
    }

    // ---- theta0 segment-sum path: self-scan idx for this block's group ----
    const int bb    = blockIdx.x - 128;
    const int g     = bb & 1023;
    const int chunk = bb >> 10;

    __shared__ int rows[64];
    __shared__ int cnt;
    __shared__ float wsum[4];
    if (t == 0) cnt = 0;
    __syncthreads();
    #pragma unroll
    for (int i = 0; i < 32; ++i) {
        const int j = t + i * 256;
        if (idx[j] == g) { const int p = atomicAdd(&cnt, 1); if (p < 64) rows[p] = j; }
    }
    __syncthreads();
    const int n = cnt;
    const float4* base = theta0 + (size_t)chunk * 256 + t;  // row stride = 1024 float4

    float4 a0 = {0,0,0,0}, a1 = {0,0,0,0}, a2 = {0,0,0,0}, a3 = {0,0,0,0};
    if (n <= 64) {
        int r = 0;
        for (; r + 4 <= n; r += 4) {
            const float4 v0 = base[(size_t)rows[r + 0] * 1024];
            const float4 v1 = base[(size_t)rows[r + 1] * 1024];
            const float4 v2 = base[(size_t)rows[r + 2] * 1024];
            const float4 v3 = base[(size_t)rows[r + 3] * 1024];
            acc4(a0, exp4(v0));
            acc4(a1, exp4(v1));
            acc4(a2, exp4(v2));
            acc4(a3, exp4(v3));
        }
        for (; r < n; ++r) acc4(a0, exp4(base[(size_t)rows[r] * 1024]));
    } else {
        // pathological overflow (never for this data) — slow but correct
        for (int j = 0; j < 8192; ++j)
            if (idx[j] == g) acc4(a0, exp4(base[(size_t)j * 1024]));
    }

    float4 s;
    s.x = a0.x + a1.x + a2.x + a3.x;
    s.y = a0.y + a1.y + a2.y + a3.y;
    s.z = a0.z + a1.z + a2.z + a3.z;
    s.w = a0.w + a1.w + a2.w + a3.w;

    const size_t o = (size_t)g * 1024 + (size_t)chunk * 256 + t;
    if (s0) {
        s0[o] = s;
    } else {
        const int c = chunk * 1024 + t * 4;
        atomicAdd(&p2[c + 0], s.x);
        atomicAdd(&p2[c + 1], s.y);
        atomicAdd(&p2[c + 2], s.z);
        atomicAdd(&p2[c + 3], s.w);
    }
    const float4 ob = obs0[o];
    const float dx = ob.x - s.x, dy = ob.y - s.y, dz = ob.z - s.z, dw = ob.w - s.w;
    float l = dx*dx + dy*dy + dz*dz + dw*dw;
    l = wave_reduce(l);
    if (lane == 0) wsum[wave] = l;
    __syncthreads();
    if (t == 0) atomicAdd(lossA, wsum[0] + wsum[1] + wsum[2] + wsum[3]);
}

// ================= K3F: column sums of s0 + loss_c; last block does loss_b + combine =========
// grid = 64, block = 1024
__global__ __launch_bounds__(1024) void K3F(const float* __restrict__ s0,
                                            const float* __restrict__ obs2,
                                            const float* __restrict__ lossA,
                                            float* __restrict__ lossC,
                                            int* __restrict__ ticket,
                                            const float* __restrict__ m1,
                                            const float* __restrict__ obs1,
                                            float* __restrict__ out) {
    __shared__ float part[16][64];
    __shared__ int isLast;
    const int tid = threadIdx.x, lane = tid & 63, wave = tid >> 6;
    const int col = blockIdx.x * 64 + lane;
    const float* p = s0 + (size_t)wave * 4096 + col;
    float a = 0.f;
    #pragma unroll 4
    for (int g = 0; g < 64; ++g) a += p[(size_t)g * 16 * 4096];
    part[wave][lane] = a;
    __syncthreads();
    if (wave == 0) {
        float s = 0.f;
        #pragma unroll
        for (int k = 0; k < 16; ++k) s += part[k][lane];
        const float d = obs2[col] - s;
        const float l = wave_reduce(d * d);
        if (lane == 0) {
            atomicAdd(lossC, l);
            __threadfence();
        }
    }
    __syncthreads();
    if (tid == 0) isLast = (atomicAdd(ticket, 1) == 63) ? 1 : 0;
    __syncthreads();
    if (!isLast) return;

    // ---- final: loss_b + combine ----
    __shared__ float wb[16];
    float lb = 0.f;
    if (tid < 512) { const float d = obs1[tid] - m1[tid]; lb = d * d; }
    lb = wave_reduce(lb);
    if (lane == 0) wb[wave] = lb;
    __syncthreads();
    if (tid == 0) {
        float sb = 0.f;
        #pragma unroll
        for (int i = 0; i < 16; ++i) sb += wb[i];
        const float sc = atomicAdd(lossC, 0.f);   // coherent L2 read
        const float la = lossA[0] / 4194304.f;
        const float lbf = sb / 512.f;
        const float lcf = 0.5f * sc / 4096.f;
        out[0] = (la + lbf + lcf) / 3.f;
    }
}

// ================= K4FB: fallback final (loss_b + loss_c from p2 + combine) =================
// grid = 1, block = 512
__global__ __launch_bounds__(512) void K4FB(const float* __restrict__ m1,
                                            const float* __restrict__ obs1,
                                            const float* __restrict__ losses,
                                            const float* __restrict__ p2,
                                            const float* __restrict__ obs2,
                                            float* __restrict__ out) {
    __shared__ float wb[8];
    __shared__ float wc[8];
    const int t = threadIdx.x, lane = t & 63, wave = t >> 6;
    const float d = obs1[t] - m1[t];
    const float lb = wave_reduce(d * d);
    float acc = 0.f;
    #pragma unroll
    for (int i = 0; i < 8; ++i) {
        const int c = t + i * 512;
        const float dd = obs2[c] - p2[c];
        acc += dd * dd;
    }
    const float lc = wave_reduce(acc);
    if (lane == 0) { wb[wave] = lb; wc[wave] = lc; }
    __syncthreads();
    if (t == 0) {
        float sb = 0.f, sc = 0.f;
        #pragma unroll
        for (int i = 0; i < 8; ++i) { sb += wb[i]; sc += wc[i]; }
        const float la = losses[0] / 4194304.f;
        out[0] = (la + sb / 512.f + 0.5f * sc / 4096.f) / 3.f;
    }
}

extern "C" void kernel_launch(void* const* d_in, const int* in_sizes, int n_in,
                              void* d_out, int out_size, void* d_ws, size_t ws_size,
                              hipStream_t stream) {
    const float* theta0   = (const float*)d_in[0];   // [8192,4096]
    const float* theta1   = (const float*)d_in[1];   // [4096,2048]
    const float* obs0     = (const float*)d_in[2];   // [1024,4096]
    const float* obs1     = (const float*)d_in[3];   // [512]
    const float* obs2     = (const float*)d_in[4];   // [4096]
    const int*   idx0     = (const int*)d_in[5];     // [8192]
    const float* mapping1 = (const float*)d_in[6];   // [512,4096]
    float* out = (float*)d_out;

    char* ws = (char*)d_ws;
    float* losses = (float*)(ws + 0);      // [0]=lossA, [2]=lossC
    int*   ticket = (int*)(ws + 12);
    float* m1     = (float*)(ws + 256);    // 512 floats, ends 2304
    float* p2     = (float*)(ws + 4096);   // 4096 floats (fallback only), ends 20480
    float* s0     = (float*)(ws + 65536);  // 16 MB

    const size_t NEED = 65536 + (size_t)1024 * 4096 * 4;
    const bool path1 = ws_size >= NEED;

    hipMemsetAsync(ws, 0, 20480, stream);  // losses + ticket + m1 + p2

    if (path1) {
        MEGA<<<4224, 256, 0, stream>>>((const float4*)theta0, (const float4*)obs0, idx0,
                                       (const float4*)theta1, (const float4*)mapping1,
                                       (float4*)s0, p2, &losses[0], m1);
        K3F<<<64, 1024, 0, stream>>>(s0, obs2, &losses[0], &losses[2], ticket,
                                     m1, obs1, out);
    } else {
        MEGA<<<4224, 256, 0, stream>>>((const float4*)theta0, (const float4*)obs0, idx0,
                                       (const float4*)theta1, (const float4*)mapping1,
                                       nullptr, p2, &losses[0], m1);
        K4FB<<<1, 512, 0, stream>>>(m1, obs1, losses, p2, obs2, out);
    }
}

// Round 5
// 257.072 us; speedup vs baseline: 1.0511x; 1.0511x over previous
//
#include <hip/hip_runtime.h>

__device__ __forceinline__ float4 exp4(float4 v) {
    float4 r;
    r.x = __expf(v.x); r.y = __expf(v.y); r.z = __expf(v.z); r.w = __expf(v.w);
    return r;
}

__device__ __forceinline__ void acc4(float4& a, float4 e) {
    a.x += e.x; a.y += e.y; a.z += e.z; a.w += e.w;
}

__device__ __forceinline__ float wave_reduce(float v) {
    #pragma unroll
    for (int off = 32; off > 0; off >>= 1) v += __shfl_down(v, off, 64);
    return v;
}

// async 16B global -> LDS (no VGPR destination; counted by vmcnt)
__device__ __forceinline__ void load_lds16(const void* g, void* l) {
    __builtin_amdgcn_global_load_lds(
        (const __attribute__((address_space(1))) void*)g,
        (__attribute__((address_space(3))) void*)l, 16, 0, 0);
}

#define BATCH 8

// ================= MEGA: blocks 0..127 theta1 path; blocks 128..4223 theta0 segment sums =====
// block = 256
__global__ __launch_bounds__(256) void MEGA(const float4* __restrict__ theta0,
                                            const float4* __restrict__ obs0,
                                            const int* __restrict__ idx,
                                            const float4* __restrict__ theta1,
                                            const float4* __restrict__ mapping1,
                                            float4* __restrict__ s0,   // nullptr => p2-atomics
                                            float* __restrict__ p2,
                                            float* __restrict__ lossA,
                                            float* __restrict__ m1) {
    __shared__ float stage[BATCH][1024];   // 32 KB row staging
    __shared__ int rows[64];
    __shared__ int cnt;
    __shared__ float wsum[4];

    const int t = threadIdx.x, lane = t & 63, wave = t >> 6;

    if (blockIdx.x < 128) {
        // ---- theta1 row sums of exp, then mapping1 slice -> m1 atomics ----
        const int b2 = blockIdx.x;               // col-slice of 32 p1-entries
        float* p1s = (float*)rows;               // reuse LDS
        #pragma unroll
        for (int rr = 0; rr < 8; ++rr) {
            const int lr = wave * 8 + rr;        // 0..31
            const float4* rp = theta1 + (size_t)(b2 * 32 + lr) * 512;
            float a = 0.f;
            #pragma unroll
            for (int i = 0; i < 8; ++i) {
                const float4 x = rp[lane + i * 64];
                a += __expf(x.x) + __expf(x.y) + __expf(x.z) + __expf(x.w);
            }
            a = wave_reduce(a);
            if (lane == 0) p1s[lr] = a;
        }
        __syncthreads();
        #pragma unroll
        for (int rr = 0; rr < 2; ++rr) {
            const int r = t * 2 + rr;            // 0..511
            const float4* mp = mapping1 + (size_t)r * 1024 + b2 * 8;
            float s = 0.f;
            #pragma unroll
            for (int j = 0; j < 8; ++j) {
                const float4 m = mp[j];
                s += m.x * p1s[j*4+0] + m.y * p1s[j*4+1]
                   + m.z * p1s[j*4+2] + m.w * p1s[j*4+3];
            }
            atomicAdd(&m1[r], s);
        }
        return;
    }

    // ---- theta0 segment-sum path ----
    const int bb    = blockIdx.x - 128;
    const int g     = bb & 1023;
    const int chunk = bb >> 10;

    if (t == 0) cnt = 0;
    __syncthreads();
    // int4 scan of the 32 KB idx array (L2/L3-broadcast-resident)
    const int4* idx4 = (const int4*)idx;
    #pragma unroll
    for (int i = 0; i < 8; ++i) {
        const int j4 = t + i * 256;
        const int4 v = idx4[j4];
        if (v.x == g) { const int p = atomicAdd(&cnt, 1); if (p < 64) rows[p] = j4 * 4 + 0; }
        if (v.y == g) { const int p = atomicAdd(&cnt, 1); if (p < 64) rows[p] = j4 * 4 + 1; }
        if (v.z == g) { const int p = atomicAdd(&cnt, 1); if (p < 64) rows[p] = j4 * 4 + 2; }
        if (v.w == g) { const int p = atomicAdd(&cnt, 1); if (p < 64) rows[p] = j4 * 4 + 3; }
    }
    __syncthreads();
    const int n = cnt;

    float4 a0 = {0,0,0,0}, a1 = {0,0,0,0}, a2 = {0,0,0,0}, a3 = {0,0,0,0};
    if (n <= 64) {
        for (int t0 = 0; t0 < n; t0 += BATCH) {
            const int m = min(BATCH, n - t0);
            // fire all row loads async into LDS: 1 KB per wave per row, no VGPR dest
            for (int s = 0; s < m; ++s) {
                const float4* g4 = theta0 + (size_t)rows[t0 + s] * 1024
                                 + (size_t)chunk * 256 + wave * 64 + lane;
                load_lds16(g4, &stage[s][wave * 256]);
            }
            __syncthreads();   // drains vmcnt(0): all staged
            for (int s = 0; s < m; ++s) {
                const float4 v = *(const float4*)&stage[s][t * 4];
                switch (s & 3) {
                    case 0: acc4(a0, exp4(v)); break;
                    case 1: acc4(a1, exp4(v)); break;
                    case 2: acc4(a2, exp4(v)); break;
                    default: acc4(a3, exp4(v)); break;
                }
            }
            if (t0 + BATCH < n) __syncthreads();  // protect stage reuse
        }
    } else {
        // pathological overflow (never for this data) — slow but correct
        const float4* base = theta0 + (size_t)chunk * 256 + t;
        for (int j = 0; j < 8192; ++j)
            if (idx[j] == g) acc4(a0, exp4(base[(size_t)j * 1024]));
    }

    float4 s;
    s.x = a0.x + a1.x + a2.x + a3.x;
    s.y = a0.y + a1.y + a2.y + a3.y;
    s.z = a0.z + a1.z + a2.z + a3.z;
    s.w = a0.w + a1.w + a2.w + a3.w;

    const size_t o = (size_t)g * 1024 + (size_t)chunk * 256 + t;
    if (s0) {
        s0[o] = s;
    } else {
        const int c = chunk * 1024 + t * 4;
        atomicAdd(&p2[c + 0], s.x);
        atomicAdd(&p2[c + 1], s.y);
        atomicAdd(&p2[c + 2], s.z);
        atomicAdd(&p2[c + 3], s.w);
    }
    const float4 ob = obs0[o];
    const float dx = ob.x - s.x, dy = ob.y - s.y, dz = ob.z - s.z, dw = ob.w - s.w;
    float l = dx*dx + dy*dy + dz*dz + dw*dw;
    l = wave_reduce(l);
    if (lane == 0) wsum[wave] = l;
    __syncthreads();
    if (t == 0) atomicAdd(lossA, wsum[0] + wsum[1] + wsum[2] + wsum[3]);
}

// ================= K3F: column sums of s0 + loss_c; last block does loss_b + combine =========
// grid = 64, block = 1024
__global__ __launch_bounds__(1024) void K3F(const float* __restrict__ s0,
                                            const float* __restrict__ obs2,
                                            const float* __restrict__ lossA,
                                            float* __restrict__ lossC,
                                            int* __restrict__ ticket,
                                            const float* __restrict__ m1,
                                            const float* __restrict__ obs1,
                                            float* __restrict__ out) {
    __shared__ float part[16][64];
    __shared__ int isLast;
    const int tid = threadIdx.x, lane = tid & 63, wave = tid >> 6;
    const int col = blockIdx.x * 64 + lane;
    const float* p = s0 + (size_t)wave * 4096 + col;
    float a = 0.f;
    #pragma unroll 4
    for (int g = 0; g < 64; ++g) a += p[(size_t)g * 16 * 4096];
    part[wave][lane] = a;
    __syncthreads();
    if (wave == 0) {
        float s = 0.f;
        #pragma unroll
        for (int k = 0; k < 16; ++k) s += part[k][lane];
        const float d = obs2[col] - s;
        const float l = wave_reduce(d * d);
        if (lane == 0) {
            atomicAdd(lossC, l);
            __threadfence();
        }
    }
    __syncthreads();
    if (tid == 0) isLast = (atomicAdd(ticket, 1) == 63) ? 1 : 0;
    __syncthreads();
    if (!isLast) return;

    // ---- final: loss_b + combine ----
    __shared__ float wb[16];
    float lb = 0.f;
    if (tid < 512) { const float d = obs1[tid] - m1[tid]; lb = d * d; }
    lb = wave_reduce(lb);
    if (lane == 0) wb[wave] = lb;
    __syncthreads();
    if (tid == 0) {
        float sb = 0.f;
        #pragma unroll
        for (int i = 0; i < 16; ++i) sb += wb[i];
        const float sc = atomicAdd(lossC, 0.f);   // coherent L2 read
        const float la = lossA[0] / 4194304.f;
        const float lbf = sb / 512.f;
        const float lcf = 0.5f * sc / 4096.f;
        out[0] = (la + lbf + lcf) / 3.f;
    }
}

// ================= K4FB: fallback final (loss_b + loss_c from p2 + combine) =================
// grid = 1, block = 512
__global__ __launch_bounds__(512) void K4FB(const float* __restrict__ m1,
                                            const float* __restrict__ obs1,
                                            const float* __restrict__ losses,
                                            const float* __restrict__ p2,
                                            const float* __restrict__ obs2,
                                            float* __restrict__ out) {
    __shared__ float wb[8];
    __shared__ float wc[8];
    const int t = threadIdx.x, lane = t & 63, wave = t >> 6;
    const float d = obs1[t] - m1[t];
    const float lb = wave_reduce(d * d);
    float acc = 0.f;
    #pragma unroll
    for (int i = 0; i < 8; ++i) {
        const int c = t + i * 512;
        const float dd = obs2[c] - p2[c];
        acc += dd * dd;
    }
    const float lc = wave_reduce(acc);
    if (lane == 0) { wb[wave] = lb; wc[wave] = lc; }
    __syncthreads();
    if (t == 0) {
        float sb = 0.f, sc = 0.f;
        #pragma unroll
        for (int i = 0; i < 8; ++i) { sb += wb[i]; sc += wc[i]; }
        const float la = losses[0] / 4194304.f;
        out[0] = (la + sb / 512.f + 0.5f * sc / 4096.f) / 3.f;
    }
}

extern "C" void kernel_launch(void* const* d_in, const int* in_sizes, int n_in,
                              void* d_out, int out_size, void* d_ws, size_t ws_size,
                              hipStream_t stream) {
    const float* theta0   = (const float*)d_in[0];   // [8192,4096]
    const float* theta1   = (const float*)d_in[1];   // [4096,2048]
    const float* obs0     = (const float*)d_in[2];   // [1024,4096]
    const float* obs1     = (const float*)d_in[3];   // [512]
    const float* obs2     = (const float*)d_in[4];   // [4096]
    const int*   idx0     = (const int*)d_in[5];     // [8192]
    const float* mapping1 = (const float*)d_in[6];   // [512,4096]
    float* out = (float*)d_out;

    char* ws = (char*)d_ws;
    float* losses = (float*)(ws + 0);      // [0]=lossA, [2]=lossC
    int*   ticket = (int*)(ws + 12);
    float* m1     = (float*)(ws + 256);    // 512 floats, ends 2304
    float* p2     = (float*)(ws + 4096);   // 4096 floats (fallback only), ends 20480
    float* s0     = (float*)(ws + 65536);  // 16 MB

    const size_t NEED = 65536 + (size_t)1024 * 4096 * 4;
    const bool path1 = ws_size >= NEED;

    hipMemsetAsync(ws, 0, 20480, stream);  // losses + ticket + m1 + p2

    if (path1) {
        MEGA<<<4224, 256, 0, stream>>>((const float4*)theta0, (const float4*)obs0, idx0,
                                       (const float4*)theta1, (const float4*)mapping1,
                                       (float4*)s0, p2, &losses[0], m1);
        K3F<<<64, 1024, 0, stream>>>(s0, obs2, &losses[0], &losses[2], ticket,
                                     m1, obs1, out);
    } else {
        MEGA<<<4224, 256, 0, stream>>>((const float4*)theta0, (const float4*)obs0, idx0,
                                       (const float4*)theta1, (const float4*)mapping1,
                                       nullptr, p2, &losses[0], m1);
        K4FB<<<1, 512, 0, stream>>>(m1, obs1, losses, p2, obs2, out);
    }
}